// Round 19
// baseline (185.947 us; speedup 1.0000x reference)
//
#include <hip/hip_runtime.h>
#include <cstdint>

typedef _Float16 f16;
typedef _Float16 f16x4 __attribute__((ext_vector_type(4)));
typedef _Float16 f16x8 __attribute__((ext_vector_type(8)));
typedef float f32x4 __attribute__((ext_vector_type(4)));

constexpr int NB = 4, NT = 2048, NC = 1024, NH = 16, HS = 64;
constexpr int Mtot = NB * NT;            // 8192
constexpr int BM = 128, BN = 128;

// async global->LDS 16B (CK-style addrspace casts)
__device__ __forceinline__ void gll16(const f16* g, f16* l) {
  __builtin_amdgcn_global_load_lds(
      (const __attribute__((address_space(1))) unsigned int*)(uintptr_t)g,
      (__attribute__((address_space(3))) unsigned int*)(uintptr_t)l, 16, 0, 0);
}

// ---------------------------------------------------------------------------
// prep: fused  (a) X fp32 -> f16   (b) W_qkv / W_proj fp32 -> transposed f16
// ---------------------------------------------------------------------------
__global__ __launch_bounds__(256) void prep(
    const float* __restrict__ X, const float* __restrict__ Wq,
    const float* __restrict__ Wp,
    f16* __restrict__ Xh, f16* __restrict__ Wqt, f16* __restrict__ Wpt)
{
  const int bx = blockIdx.x;
  const int t = threadIdx.x;
  if (bx < 4096) {
    const size_t i = ((size_t)bx * 256 + t) * 8;
    float4 a = *reinterpret_cast<const float4*>(X + i);
    float4 b = *reinterpret_cast<const float4*>(X + i + 4);
    f16x8 o;
    o[0] = (f16)a.x; o[1] = (f16)a.y; o[2] = (f16)a.z; o[3] = (f16)a.w;
    o[4] = (f16)b.x; o[5] = (f16)b.y; o[6] = (f16)b.z; o[7] = (f16)b.w;
    *reinterpret_cast<f16x8*>(Xh + i) = o;
    return;
  }
  __shared__ __align__(16) f16 Ts[64 * 72];
  const int t2 = bx - 4096;
  const int nt = t2 & 63;
  const int k0 = (t2 >> 6) * 64;
  const float* src; f16* dst; int Ndim, n0;
  if (nt < 48) { src = Wq; dst = Wqt; Ndim = 3 * NC; n0 = nt * 64; }
  else         { src = Wp; dst = Wpt; Ndim = NC;     n0 = (nt - 48) * 64; }
  const int kl = t >> 2, nb = (t & 3) * 16;
#pragma unroll
  for (int i = 0; i < 4; ++i) {
    float4 vv = *reinterpret_cast<const float4*>(
        src + (size_t)(k0 + kl) * Ndim + n0 + nb + 4 * i);
    f16x4 h; h[0] = (f16)vv.x; h[1] = (f16)vv.y; h[2] = (f16)vv.z; h[3] = (f16)vv.w;
    *reinterpret_cast<f16x4*>(&Ts[kl * 72 + nb + 4 * i]) = h;
  }
  __syncthreads();
  const int nl = t >> 2, kb = (t & 3) * 16;
#pragma unroll
  for (int i = 0; i < 2; ++i) {
    f16x8 o;
#pragma unroll
    for (int j = 0; j < 8; ++j) o[j] = Ts[(kb + 8 * i + j) * 72 + nl];
    *reinterpret_cast<f16x8*>(dst + (size_t)(n0 + nl) * NC + k0 + kb + 8 * i) = o;
  }
}

// ---------------------------------------------------------------------------
// f16 GEMM, 128x128 tile, BK=64, global_load_lds staging (pre-swizzled src).
// MODE 0: qkv epilogue. V written as the per-64-token-tile tau-image:
//   Vh[bh][tile][d][tau(t&63)],  tau: [b5|b4|b3b2|b1b0] -> [b5|b3b2|b4|b1b0]
// ---------------------------------------------------------------------------
template <int MODE>
__global__ __launch_bounds__(256) void gemm_f16(
    const f16* __restrict__ A, const f16* __restrict__ Bt,
    const float* __restrict__ bias,
    f16* __restrict__ Qh, f16* __restrict__ Kh, f16* __restrict__ Vh,
    float* __restrict__ Out, int ntiles)
{
  __shared__ __align__(16) f16 As[BM * 64];
  __shared__ __align__(16) f16 Bs[BN * 64];
  const int tid = threadIdx.x;
  const int flat = blockIdx.x;
  const int cpx = gridDim.x >> 3;
  const int v = (flat & 7) * cpx + (flat >> 3);       // XCD-contig chunks
  const int m0 = (v / ntiles) * BM;
  const int n0 = (v % ntiles) * BN;
  const int w = tid >> 6, l = tid & 63;
  const int wr = w >> 1, wc = w & 1;
  const int lr = l & 15, hi = l >> 4;

  f32x4 acc[4][4];
#pragma unroll
  for (int i = 0; i < 4; ++i)
#pragma unroll
    for (int j = 0; j < 4; ++j) acc[i][j] = (f32x4){0.f, 0.f, 0.f, 0.f};

  const int lrow = l >> 3;
  const int lsrc = ((l & 7) ^ lrow) * 8;

  for (int k0 = 0; k0 < NC; k0 += 64) {
    __syncthreads();
#pragma unroll
    for (int i = 0; i < 4; ++i) {
      const int rr = 32 * w + 8 * i;
      gll16(A  + (size_t)(m0 + rr + lrow) * NC + k0 + lsrc, &As[rr * 64]);
      gll16(Bt + (size_t)(n0 + rr + lrow) * NC + k0 + lsrc, &Bs[rr * 64]);
    }
    __syncthreads();
#pragma unroll
    for (int kk = 0; kk < 2; ++kk) {
      f16x8 a[4], b[4];
#pragma unroll
      for (int mi = 0; mi < 4; ++mi) {
        int row = wr * 64 + mi * 16 + lr;
        int idx = (row * 64 + kk * 32 + hi * 8) ^ ((row & 7) << 3);
        a[mi] = *reinterpret_cast<const f16x8*>(&As[idx]);
      }
#pragma unroll
      for (int ni = 0; ni < 4; ++ni) {
        int row = wc * 64 + ni * 16 + lr;
        int idx = (row * 64 + kk * 32 + hi * 8) ^ ((row & 7) << 3);
        b[ni] = *reinterpret_cast<const f16x8*>(&Bs[idx]);
      }
#pragma unroll
      for (int mi = 0; mi < 4; ++mi)
#pragma unroll
        for (int ni = 0; ni < 4; ++ni)
          acc[mi][ni] = __builtin_amdgcn_mfma_f32_16x16x32_f16(
              a[mi], b[ni], acc[mi][ni], 0, 0, 0);
    }
  }

  if (MODE == 0) {
#pragma unroll
    for (int ni = 0; ni < 4; ++ni) {
      int colg = n0 + wc * 64 + ni * 16 + lr;
      int which = colg >> 10;
      int c = colg & (NC - 1);
      int h = c >> 6, d = c & 63;
      float bv = bias[colg];
      if (which == 2) {
#pragma unroll
        for (int mi = 0; mi < 4; ++mi) {
          int rowg = m0 + wr * 64 + mi * 16 + hi * 4;   // t base, %4 == 0
          int b = rowg >> 11, tt = rowg & (NT - 1);
          int slot = ((tt >> 5) & 1) * 32 + ((tt >> 2) & 3) * 8 + ((tt >> 4) & 1) * 4;
          f16x4 pk;
#pragma unroll
          for (int r = 0; r < 4; ++r) pk[r] = (f16)(acc[mi][ni][r] + bv);
          *reinterpret_cast<f16x4*>(
              &Vh[(size_t)(b * NH + h) * NT * HS + (tt >> 6) * 4096 + d * 64 + slot]) = pk;
        }
      } else {
        f16* dst = (which == 0) ? Qh : Kh;
#pragma unroll
        for (int mi = 0; mi < 4; ++mi) {
#pragma unroll
          for (int r = 0; r < 4; ++r) {
            int rowg = m0 + wr * 64 + mi * 16 + hi * 4 + r;
            int b = rowg >> 11, t = rowg & (NT - 1);
            dst[(((size_t)(b * NH + h) * NT) + t) * HS + d] =
                (f16)(acc[mi][ni][r] + bv);
          }
        }
      }
    }
  } else {
#pragma unroll
    for (int ni = 0; ni < 4; ++ni) {
      int colg = n0 + wc * 64 + ni * 16 + lr;
      float bv = bias[colg];
#pragma unroll
      for (int mi = 0; mi < 4; ++mi) {
#pragma unroll
        for (int r = 0; r < 4; ++r) {
          int rowg = m0 + wr * 64 + mi * 16 + hi * 4 + r;
          Out[(size_t)rowg * NC + colg] = acc[mi][ni][r] + bv;
        }
      }
    }
  }
}

// ---------------------------------------------------------------------------
// MFMA flash attention, causal. Block = 2 waves x 64 q-rows; block owns the
// balanced pair {qt0=pairi, qt1=31-pairi} MERGED into one jt loop over
// 0..qt1: each K/V tile staged ONCE (17..32 stages vs 33), seg1 computed
// every tile, seg0 while jt<=qt0; total compute stays uniform (33).
// K and V staged via global_load_lds with pre-swizzled sources (no commit
// writes, no prefetch registers). V is the gemm-produced tau-image.
// Per-tile compute = r18's dual-mt MFMA cluster + interleaved dual softmax.
// __launch_bounds__(128,2): 256-reg cap (4/EU promise spills: r3/r11).
// ---------------------------------------------------------------------------
__global__ __launch_bounds__(128, 2) void flash_attn(
    const f16* __restrict__ Qh, const f16* __restrict__ Kh,
    const f16* __restrict__ Vh, f16* __restrict__ att)
{
  __shared__ __align__(16) f16 Ks[2][64 * 64];   // [kv][d], d-swizzled by row
  __shared__ __align__(16) f16 Vt[2][64 * 64];   // [d][slot], slot-swizzled by d

  const int tid = threadIdx.x;
  const int w = tid >> 6, l = tid & 63;
  const int lr = l & 15, g = l >> 4;

  const int flat = blockIdx.x;                    // 0..1023
  const int v = (flat & 7) * 128 + (flat >> 3);   // XCD-contig chunks
  const int pairi = v & 15;                       // 0..15
  const int bh = v >> 4;                          // 0..63

  const f16* Qb = Qh + (size_t)bh * NT * HS;
  const f16* Kb = Kh + (size_t)bh * NT * HS;
  const f16* Vb = Vh + (size_t)bh * NT * HS;
  const int ob = bh >> 4, oh = bh & (NH - 1);

  const int qt0 = pairi, qt1 = 31 - pairi;        // qt1 >= 16 > qt0
  const int qb0 = qt0 * 64 + w * 32;
  const int qb1 = qt1 * 64 + w * 32;

  const int lrow = l >> 3;                        // 0..7
  const int lsrc = ((l & 7) ^ lrow) * 8;          // K src swizzle (f16 units)

  // ---- prologue: stage tile 0 (K + V) via global_load_lds ----
#pragma unroll
  for (int i = 0; i < 4; ++i) {
    const int rr = 32 * w + 8 * i;
    const int row = rr + lrow;
    gll16(Kb + (size_t)row * HS + lsrc, &Ks[0][rr * 64]);
    gll16(Vb + (size_t)row * 64 + (((l & 7) ^ ((row + (row >> 3)) & 7)) * 8),
          &Vt[0][rr * 64]);
  }

  // Q fragments for both segments, scale (1/8)*log2(e) folded
  f16x8 qB0[2][2], qB1[2][2];
#pragma unroll
  for (int mt = 0; mt < 2; ++mt)
#pragma unroll
    for (int ds = 0; ds < 2; ++ds) {
      f16x8 t0 = *reinterpret_cast<const f16x8*>(
          Qb + (size_t)(qb0 + 16 * mt + lr) * HS + 32 * ds + 8 * g);
      f16x8 t1 = *reinterpret_cast<const f16x8*>(
          Qb + (size_t)(qb1 + 16 * mt + lr) * HS + 32 * ds + 8 * g);
#pragma unroll
      for (int j = 0; j < 8; ++j) {
        t0[j] = t0[j] * (f16)0.18033688f;
        t1[j] = t1[j] * (f16)0.18033688f;
      }
      qB0[mt][ds] = t0; qB1[mt][ds] = t1;
    }

  f32x4 Ot0[2][4], Ot1[2][4];
  float m_run0[2], l_run0[2], m_run1[2], l_run1[2];
#pragma unroll
  for (int mt = 0; mt < 2; ++mt) {
#pragma unroll
    for (int dt = 0; dt < 4; ++dt) {
      Ot0[mt][dt] = (f32x4){0.f, 0.f, 0.f, 0.f};
      Ot1[mt][dt] = (f32x4){0.f, 0.f, 0.f, 0.f};
    }
    m_run0[mt] = -INFINITY; l_run0[mt] = 0.f;
    m_run1[mt] = -INFINITY; l_run1[mt] = 0.f;
  }

  for (int jt = 0; jt <= qt1; ++jt) {
    const int cur = jt & 1;
    __syncthreads();                    // tile jt landed (drains gll16 queue)

    // ---- issue tile jt+1 into alternate buffers ----
    if (jt < qt1) {
      const int nj = jt + 1;
#pragma unroll
      for (int i = 0; i < 4; ++i) {
        const int rr = 32 * w + 8 * i;
        const int row = rr + lrow;
        gll16(Kb + (size_t)(nj * 64 + row) * HS + lsrc, &Ks[cur ^ 1][rr * 64]);
        gll16(Vb + (size_t)nj * 4096 + (size_t)row * 64 +
                  (((l & 7) ^ ((row + (row >> 3)) & 7)) * 8),
              &Vt[cur ^ 1][rr * 64]);
      }
    }

    // ---- K fragments (A-operand), shared by both segments ----
    f16x8 aK[4][2];
#pragma unroll
    for (int kt2 = 0; kt2 < 4; ++kt2) {
      int row = 16 * kt2 + lr;
#pragma unroll
      for (int ds = 0; ds < 2; ++ds)
        aK[kt2][ds] = *reinterpret_cast<const f16x8*>(
            &Ks[cur][row * 64 + ((32 * ds + 8 * g) ^ ((row & 7) << 3))]);
    }

    // ---- per-segment compute (r18 body) ----
    auto seg_compute = [&](int qbase, const f16x8 (&qB)[2][2],
                           f32x4 (&Ot)[2][4], float (&m_run)[2],
                           float (&l_run)[2]) {
      const bool needMask = (jt * 64 + 63) > qbase;
      f32x4 St[2][4];
#pragma unroll
      for (int mt = 0; mt < 2; ++mt)
#pragma unroll
        for (int kt2 = 0; kt2 < 4; ++kt2) St[mt][kt2] = (f32x4){0.f, 0.f, 0.f, 0.f};
      __builtin_amdgcn_s_setprio(1);
#pragma unroll
      for (int mt = 0; mt < 2; ++mt)
#pragma unroll
        for (int kt2 = 0; kt2 < 4; ++kt2)
#pragma unroll
          for (int ds = 0; ds < 2; ++ds)
            St[mt][kt2] = __builtin_amdgcn_mfma_f32_16x16x32_f16(
                aK[kt2][ds], qB[mt][ds], St[mt][kt2], 0, 0, 0);
      __builtin_amdgcn_s_setprio(0);

      if (needMask) {
#pragma unroll
        for (int mt = 0; mt < 2; ++mt) {
          const int qg = qbase + 16 * mt + lr;
#pragma unroll
          for (int kt2 = 0; kt2 < 4; ++kt2)
#pragma unroll
            for (int r = 0; r < 4; ++r)
              if ((jt * 64 + 16 * kt2 + 4 * g + r) > qg) St[mt][kt2][r] = -INFINITY;
        }
      }

      float pm0 = -INFINITY, pm1 = -INFINITY;
#pragma unroll
      for (int kt2 = 0; kt2 < 4; ++kt2)
#pragma unroll
        for (int r = 0; r < 4; ++r) {
          pm0 = fmaxf(pm0, St[0][kt2][r]);
          pm1 = fmaxf(pm1, St[1][kt2][r]);
        }
      {
        float a0 = __shfl_xor(pm0, 16), a1 = __shfl_xor(pm1, 16);
        pm0 = fmaxf(pm0, a0); pm1 = fmaxf(pm1, a1);
        a0 = __shfl_xor(pm0, 32); a1 = __shfl_xor(pm1, 32);
        pm0 = fmaxf(pm0, a0); pm1 = fmaxf(pm1, a1);
      }
      float mo0 = m_run[0], mo1 = m_run[1];
      const bool need0 = !__all(pm0 <= mo0 + 8.0f);
      const bool need1 = !__all(pm1 <= mo1 + 8.0f);
      if (need0) {
        float mn = fmaxf(mo0, pm0);
        float al = exp2f(mo0 - mn);
        l_run[0] *= al;
#pragma unroll
        for (int dt = 0; dt < 4; ++dt)
#pragma unroll
          for (int r = 0; r < 4; ++r) Ot[0][dt][r] *= al;
        m_run[0] = mn; mo0 = mn;
      }
      if (need1) {
        float mn = fmaxf(mo1, pm1);
        float al = exp2f(mo1 - mn);
        l_run[1] *= al;
#pragma unroll
        for (int dt = 0; dt < 4; ++dt)
#pragma unroll
          for (int r = 0; r < 4; ++r) Ot[1][dt][r] *= al;
        m_run[1] = mn; mo1 = mn;
      }
      f16x8 pB[2][2];
      float ts0 = 0.f, ts1 = 0.f;
#pragma unroll
      for (int kt2 = 0; kt2 < 4; ++kt2)
#pragma unroll
        for (int r = 0; r < 4; ++r) {
          float p0 = exp2f(St[0][kt2][r] - mo0);
          float p1 = exp2f(St[1][kt2][r] - mo1);
          ts0 += p0; ts1 += p1;
          pB[0][kt2 >> 1][(kt2 & 1) * 4 + r] = (f16)p0;
          pB[1][kt2 >> 1][(kt2 & 1) * 4 + r] = (f16)p1;
        }
      {
        float a0 = __shfl_xor(ts0, 16), a1 = __shfl_xor(ts1, 16);
        ts0 += a0; ts1 += a1;
        a0 = __shfl_xor(ts0, 32); a1 = __shfl_xor(ts1, 32);
        ts0 += a0; ts1 += a1;
      }
      l_run[0] += ts0;
      l_run[1] += ts1;

      __builtin_amdgcn_s_setprio(1);
#pragma unroll
      for (int kt = 0; kt < 2; ++kt)
#pragma unroll
        for (int dt = 0; dt < 4; ++dt) {
          int d = 16 * dt + lr;
          int s = (d + (d >> 3)) & 7;
          f16x8 vA = *reinterpret_cast<const f16x8*>(
              &Vt[cur][d * 64 + ((32 * kt + 8 * g) ^ (s << 3))]);
#pragma unroll
          for (int mt = 0; mt < 2; ++mt)
            Ot[mt][dt] = __builtin_amdgcn_mfma_f32_16x16x32_f16(
                vA, pB[mt][kt], Ot[mt][dt], 0, 0, 0);
        }
      __builtin_amdgcn_s_setprio(0);
    };

    seg_compute(qb1, qB1, Ot1, m_run1, l_run1);        // always
    if (jt <= qt0)
      seg_compute(qb0, qB0, Ot0, m_run0, l_run0);      // small segment
  }

  // ---- epilogue: normalize, repack via Ks-aliased wave-local scratch ----
  __syncthreads();                      // all waves done reading Ks/Vt
  f16* scr = &Ks[0][0] + w * 2048;      // per-wave 32x64 region

  auto epilogue = [&](int qbase, f32x4 (&Ot)[2][4], float (&l_run)[2]) {
#pragma unroll
    for (int mt = 0; mt < 2; ++mt) {
      float inv = 1.f / l_run[mt];
      int q = 16 * mt + lr;
#pragma unroll
      for (int dt = 0; dt < 4; ++dt) {
        f16x4 ok;
#pragma unroll
        for (int r = 0; r < 4; ++r) ok[r] = (f16)(Ot[mt][dt][r] * inv);
        *reinterpret_cast<f16x4*>(
            &scr[q * 64 + ((16 * dt + 4 * g) ^ ((q & 7) << 3))]) = ok;
      }
    }
    const int orow = l >> 1;
    const int ocol = (l & 1) * 32;
#pragma unroll
    for (int i = 0; i < 4; ++i) {
      f16x8 ov = *reinterpret_cast<const f16x8*>(
          &scr[orow * 64 + ((ocol + i * 8) ^ ((orow & 7) << 3))]);
      *reinterpret_cast<f16x8*>(
          &att[((size_t)(ob * NT + qbase + orow)) * NC + oh * HS + ocol + i * 8]) = ov;
    }
  };

  epilogue(qb0, Ot0, l_run0);
  epilogue(qb1, Ot1, l_run1);
}

// ---------------------------------------------------------------------------
extern "C" void kernel_launch(void* const* d_in, const int* in_sizes, int n_in,
                              void* d_out, int out_size, void* d_ws, size_t ws_size,
                              hipStream_t stream)
{
  (void)in_sizes; (void)n_in; (void)out_size; (void)ws_size;
  const float* x     = (const float*)d_in[0];
  const float* Wqkv  = (const float*)d_in[1];
  const float* bqkv  = (const float*)d_in[2];
  const float* Wproj = (const float*)d_in[3];
  const float* bproj = (const float*)d_in[4];
  float* out = (float*)d_out;

  const size_t HE = (size_t)NB * NH * NT * HS;   // 8388608 elems per tensor
  f16* Qh  = (f16*)d_ws;
  f16* Kh  = Qh + HE;
  f16* Vh  = Kh + HE;
  f16* XA  = Vh + HE;            // Xh (pre-attn) aliases att (post-attn)
  f16* Wqt = XA + HE;            // 3072x1024
  f16* Wpt = Wqt + (size_t)3 * NC * NC;  // 1024x1024

  prep<<<dim3(4096 + 1024), 256, 0, stream>>>(x, Wqkv, Wproj, XA, Wqt, Wpt);
  gemm_f16<0><<<dim3(64 * 24), 256, 0, stream>>>(XA, Wqt, bqkv, Qh, Kh, Vh, nullptr, 24);
  flash_attn<<<dim3(1024), 128, 0, stream>>>(Qh, Kh, Vh, XA);
  gemm_f16<1><<<dim3(64 * 8), 256, 0, stream>>>(XA, Wpt, bproj, nullptr, nullptr, nullptr, out, 8);
}

// Round 20
// 181.263 us; speedup vs baseline: 1.0258x; 1.0258x over previous
//
#include <hip/hip_runtime.h>
#include <cstdint>

typedef _Float16 f16;
typedef _Float16 f16x4 __attribute__((ext_vector_type(4)));
typedef _Float16 f16x8 __attribute__((ext_vector_type(8)));
typedef float f32x4 __attribute__((ext_vector_type(4)));

constexpr int NB = 4, NT = 2048, NC = 1024, NH = 16, HS = 64;
constexpr int Mtot = NB * NT;            // 8192
constexpr int BM = 128, BN = 128;

// async global->LDS 16B (CK-style addrspace casts)
__device__ __forceinline__ void gll16(const f16* g, f16* l) {
  __builtin_amdgcn_global_load_lds(
      (const __attribute__((address_space(1))) unsigned int*)(uintptr_t)g,
      (__attribute__((address_space(3))) unsigned int*)(uintptr_t)l, 16, 0, 0);
}

// ---------------------------------------------------------------------------
// prep: fused  (a) X fp32 -> f16   (b) W_qkv / W_proj fp32 -> transposed f16
// blocks [0,4096): convert; blocks [4096,5120): transpose (64 n-tiles x 16 k0)
// ---------------------------------------------------------------------------
__global__ __launch_bounds__(256) void prep(
    const float* __restrict__ X, const float* __restrict__ Wq,
    const float* __restrict__ Wp,
    f16* __restrict__ Xh, f16* __restrict__ Wqt, f16* __restrict__ Wpt)
{
  const int bx = blockIdx.x;
  const int t = threadIdx.x;
  if (bx < 4096) {
    const size_t i = ((size_t)bx * 256 + t) * 8;
    float4 a = *reinterpret_cast<const float4*>(X + i);
    float4 b = *reinterpret_cast<const float4*>(X + i + 4);
    f16x8 o;
    o[0] = (f16)a.x; o[1] = (f16)a.y; o[2] = (f16)a.z; o[3] = (f16)a.w;
    o[4] = (f16)b.x; o[5] = (f16)b.y; o[6] = (f16)b.z; o[7] = (f16)b.w;
    *reinterpret_cast<f16x8*>(Xh + i) = o;
    return;
  }
  __shared__ __align__(16) f16 Ts[64 * 72];
  const int t2 = bx - 4096;
  const int nt = t2 & 63;                 // 0..63: 48 for Wq, 16 for Wp
  const int k0 = (t2 >> 6) * 64;          // 0..960
  const float* src; f16* dst; int Ndim, n0;
  if (nt < 48) { src = Wq; dst = Wqt; Ndim = 3 * NC; n0 = nt * 64; }
  else         { src = Wp; dst = Wpt; Ndim = NC;     n0 = (nt - 48) * 64; }
  const int kl = t >> 2, nb = (t & 3) * 16;
#pragma unroll
  for (int i = 0; i < 4; ++i) {
    float4 vv = *reinterpret_cast<const float4*>(
        src + (size_t)(k0 + kl) * Ndim + n0 + nb + 4 * i);
    f16x4 h; h[0] = (f16)vv.x; h[1] = (f16)vv.y; h[2] = (f16)vv.z; h[3] = (f16)vv.w;
    *reinterpret_cast<f16x4*>(&Ts[kl * 72 + nb + 4 * i]) = h;
  }
  __syncthreads();
  const int nl = t >> 2, kb = (t & 3) * 16;
#pragma unroll
  for (int i = 0; i < 2; ++i) {
    f16x8 o;
#pragma unroll
    for (int j = 0; j < 8; ++j) o[j] = Ts[(kb + 8 * i + j) * 72 + nl];
    *reinterpret_cast<f16x8*>(dst + (size_t)(n0 + nl) * NC + k0 + kb + 8 * i) = o;
  }
}

// ---------------------------------------------------------------------------
// f16 GEMM, 128x128 tile, BK=64, global_load_lds staging (pre-swizzled src).
// MODE 0: qkv epilogue. V is written as the per-64-token-tile tau-image:
//   Vh[bh][tile][d][tau(t&63)],  tau: [b5|b4|b3b2|b1b0] -> [b5|b3b2|b4|b1b0]
// ---------------------------------------------------------------------------
template <int MODE>
__global__ __launch_bounds__(256) void gemm_f16(
    const f16* __restrict__ A, const f16* __restrict__ Bt,
    const float* __restrict__ bias,
    f16* __restrict__ Qh, f16* __restrict__ Kh, f16* __restrict__ Vh,
    float* __restrict__ Out, int ntiles)
{
  __shared__ __align__(16) f16 As[BM * 64];
  __shared__ __align__(16) f16 Bs[BN * 64];
  const int tid = threadIdx.x;
  const int flat = blockIdx.x;
  const int cpx = gridDim.x >> 3;
  const int v = (flat & 7) * cpx + (flat >> 3);       // XCD-contig chunks
  const int m0 = (v / ntiles) * BM;
  const int n0 = (v % ntiles) * BN;
  const int w = tid >> 6, l = tid & 63;
  const int wr = w >> 1, wc = w & 1;
  const int lr = l & 15, hi = l >> 4;

  f32x4 acc[4][4];
#pragma unroll
  for (int i = 0; i < 4; ++i)
#pragma unroll
    for (int j = 0; j < 4; ++j) acc[i][j] = (f32x4){0.f, 0.f, 0.f, 0.f};

  const int lrow = l >> 3;
  const int lsrc = ((l & 7) ^ lrow) * 8;

  for (int k0 = 0; k0 < NC; k0 += 64) {
    __syncthreads();
#pragma unroll
    for (int i = 0; i < 4; ++i) {
      const int rr = 32 * w + 8 * i;
      gll16(A  + (size_t)(m0 + rr + lrow) * NC + k0 + lsrc, &As[rr * 64]);
      gll16(Bt + (size_t)(n0 + rr + lrow) * NC + k0 + lsrc, &Bs[rr * 64]);
    }
    __syncthreads();
#pragma unroll
    for (int kk = 0; kk < 2; ++kk) {
      f16x8 a[4], b[4];
#pragma unroll
      for (int mi = 0; mi < 4; ++mi) {
        int row = wr * 64 + mi * 16 + lr;
        int idx = (row * 64 + kk * 32 + hi * 8) ^ ((row & 7) << 3);
        a[mi] = *reinterpret_cast<const f16x8*>(&As[idx]);
      }
#pragma unroll
      for (int ni = 0; ni < 4; ++ni) {
        int row = wc * 64 + ni * 16 + lr;
        int idx = (row * 64 + kk * 32 + hi * 8) ^ ((row & 7) << 3);
        b[ni] = *reinterpret_cast<const f16x8*>(&Bs[idx]);
      }
#pragma unroll
      for (int mi = 0; mi < 4; ++mi)
#pragma unroll
        for (int ni = 0; ni < 4; ++ni)
          acc[mi][ni] = __builtin_amdgcn_mfma_f32_16x16x32_f16(
              a[mi], b[ni], acc[mi][ni], 0, 0, 0);
    }
  }

  if (MODE == 0) {
#pragma unroll
    for (int ni = 0; ni < 4; ++ni) {
      int colg = n0 + wc * 64 + ni * 16 + lr;
      int which = colg >> 10;
      int c = colg & (NC - 1);
      int h = c >> 6, d = c & 63;
      float bv = bias[colg];
      if (which == 2) {
        // V: tau-image, 4 consecutive t -> contiguous 4 slots -> f16x4 store
#pragma unroll
        for (int mi = 0; mi < 4; ++mi) {
          int rowg = m0 + wr * 64 + mi * 16 + hi * 4;   // t base, %4 == 0
          int b = rowg >> 11, tt = rowg & (NT - 1);
          int slot = ((tt >> 5) & 1) * 32 + ((tt >> 2) & 3) * 8 + ((tt >> 4) & 1) * 4;
          f16x4 pk;
#pragma unroll
          for (int r = 0; r < 4; ++r) pk[r] = (f16)(acc[mi][ni][r] + bv);
          *reinterpret_cast<f16x4*>(
              &Vh[(size_t)(b * NH + h) * NT * HS + (tt >> 6) * 4096 + d * 64 + slot]) = pk;
        }
      } else {
        f16* dst = (which == 0) ? Qh : Kh;
#pragma unroll
        for (int mi = 0; mi < 4; ++mi) {
#pragma unroll
          for (int r = 0; r < 4; ++r) {
            int rowg = m0 + wr * 64 + mi * 16 + hi * 4 + r;
            int b = rowg >> 11, t = rowg & (NT - 1);
            dst[(((size_t)(b * NH + h) * NT) + t) * HS + d] =
                (f16)(acc[mi][ni][r] + bv);
          }
        }
      }
    }
  } else {
#pragma unroll
    for (int ni = 0; ni < 4; ++ni) {
      int colg = n0 + wc * 64 + ni * 16 + lr;
      float bv = bias[colg];
#pragma unroll
      for (int mi = 0; mi < 4; ++mi) {
#pragma unroll
        for (int r = 0; r < 4; ++r) {
          int rowg = m0 + wr * 64 + mi * 16 + hi * 4 + r;
          Out[(size_t)rowg * NC + colg] = acc[mi][ni][r] + bv;
        }
      }
    }
  }
}

// ---------------------------------------------------------------------------
// MFMA flash attention, causal. Block = 2 waves x 64 q-rows; block does the
// balanced pair {qt, 31-qt} (uniform 33 kv-tiles) -> grid 1024. KV tile = 64,
// double-buffered (32 KiB), register prefetch, one barrier per tile.
// Swapped QK^T (St = K.Q^T). V arrives from global ALREADY tau-permuted.
// BOTH 16-q half-tiles' QK^T MFMAs issued as one cluster, then the two
// independent softmax chains run statement-interleaved (VALU of one chain
// covers the ds_bpermute/shfl latency of the other). Defer-max THR=8.
// __launch_bounds__(128,2): 256-reg cap (4/EU promise spills: r3/r11).
// ---------------------------------------------------------------------------
__global__ __launch_bounds__(128, 2) void flash_attn(
    const f16* __restrict__ Qh, const f16* __restrict__ Kh,
    const f16* __restrict__ Vh, f16* __restrict__ att)
{
  __shared__ __align__(16) f16 Ks[2][64 * 64];   // [kv][d], d-swizzled by row
  __shared__ __align__(16) f16 Vt[2][64 * 64];   // [d][slot], slot-swizzled by d

  const int tid = threadIdx.x;
  const int w = tid >> 6, l = tid & 63;
  const int lr = l & 15, g = l >> 4;

  const int flat = blockIdx.x;                    // 0..1023
  const int v = (flat & 7) * 128 + (flat >> 3);   // XCD-contig chunks
  const int pairi = v & 15;                       // 0..15
  const int bh = v >> 4;                          // 0..63

  const f16* Qb = Qh + (size_t)bh * NT * HS;
  const f16* Kb = Kh + (size_t)bh * NT * HS;
  const f16* Vb = Vh + (size_t)bh * NT * HS;
  const int ob = bh >> 4, oh = bh & (NH - 1);

  const int srow = tid >> 1;            // 0..63 (K: kv row; V: d row of tau-image)
  const int scol = (tid & 1) * 32;      // 0 or 32
  const int vs = ((srow + (srow >> 3)) & 7) << 3;   // V commit swizzle (d-row)

  f16x8 kpre[4], vpre[4];
#pragma unroll
  for (int ii = 0; ii < 4; ++ii) {
    kpre[ii] = *reinterpret_cast<const f16x8*>(Kb + (size_t)srow * HS + scol + 8 * ii);
    vpre[ii] = *reinterpret_cast<const f16x8*>(Vb + (size_t)srow * HS + scol + 8 * ii);
  }

  for (int seg = 0; seg < 2; ++seg) {
    const int qt = (seg == 0) ? pairi : 31 - pairi;
    const int qbase = qt * 64 + w * 32;
    const int jtmax = qt;

    // Q as B-operand fragments (col=lr, k=8g+j), scale (1/8)*log2(e) folded
    f16x8 qB[2][2];
#pragma unroll
    for (int mt = 0; mt < 2; ++mt)
#pragma unroll
      for (int ds = 0; ds < 2; ++ds) {
        f16x8 t = *reinterpret_cast<const f16x8*>(
            Qb + (size_t)(qbase + 16 * mt + lr) * HS + 32 * ds + 8 * g);
#pragma unroll
        for (int j = 0; j < 8; ++j) t[j] = t[j] * (f16)0.18033688f;
        qB[mt][ds] = t;
      }

    f32x4 Ot[2][4];
    float m_run[2], l_run[2];
#pragma unroll
    for (int mt = 0; mt < 2; ++mt) {
#pragma unroll
      for (int dt = 0; dt < 4; ++dt) Ot[mt][dt] = (f32x4){0.f, 0.f, 0.f, 0.f};
      m_run[mt] = -INFINITY; l_run[mt] = 0.f;
    }

    for (int jt = 0; jt <= jtmax; ++jt) {
      const int cur = jt & 1;
      // ---- commit prefetched tile to LDS (both b128-vectorized) ----
#pragma unroll
      for (int ii = 0; ii < 4; ++ii) {
        int c0 = scol + 8 * ii;
        *reinterpret_cast<f16x8*>(&Ks[cur][srow * 64 + (c0 ^ ((srow & 7) << 3))]) = kpre[ii];
        *reinterpret_cast<f16x8*>(&Vt[cur][srow * 64 + (c0 ^ vs)]) = vpre[ii];
      }
      // ---- issue next tile's global loads ----
      const bool more = (jt < jtmax) || (seg == 0);
      if (more) {
        const int nj = (jt < jtmax) ? jt + 1 : 0;
#pragma unroll
        for (int ii = 0; ii < 4; ++ii) {
          kpre[ii] = *reinterpret_cast<const f16x8*>(
              Kb + (size_t)(nj * 64 + srow) * HS + scol + 8 * ii);
          vpre[ii] = *reinterpret_cast<const f16x8*>(
              Vb + (size_t)(nj * 64 + srow) * HS + scol + 8 * ii);
        }
      }
      __syncthreads();

      const bool needMask = (jt * 64 + 63) > qbase;

      // ---- cache K fragments (A-operand) in registers, once per tile ----
      f16x8 aK[4][2];
#pragma unroll
      for (int kt2 = 0; kt2 < 4; ++kt2) {
        int row = 16 * kt2 + lr;
#pragma unroll
        for (int ds = 0; ds < 2; ++ds)
          aK[kt2][ds] = *reinterpret_cast<const f16x8*>(
              &Ks[cur][row * 64 + ((32 * ds + 8 * g) ^ ((row & 7) << 3))]);
      }

      // ---- St = K.Q^T for BOTH 16-q half-tiles in one MFMA cluster ----
      f32x4 St[2][4];
#pragma unroll
      for (int mt = 0; mt < 2; ++mt)
#pragma unroll
        for (int kt2 = 0; kt2 < 4; ++kt2) St[mt][kt2] = (f32x4){0.f, 0.f, 0.f, 0.f};
      __builtin_amdgcn_s_setprio(1);
#pragma unroll
      for (int mt = 0; mt < 2; ++mt)
#pragma unroll
        for (int kt2 = 0; kt2 < 4; ++kt2)
#pragma unroll
          for (int ds = 0; ds < 2; ++ds)
            St[mt][kt2] = __builtin_amdgcn_mfma_f32_16x16x32_f16(
                aK[kt2][ds], qB[mt][ds], St[mt][kt2], 0, 0, 0);
      __builtin_amdgcn_s_setprio(0);

      // ---- masks (both halves) ----
      if (needMask) {
#pragma unroll
        for (int mt = 0; mt < 2; ++mt) {
          const int qg = qbase + 16 * mt + lr;
#pragma unroll
          for (int kt2 = 0; kt2 < 4; ++kt2)
#pragma unroll
            for (int r = 0; r < 4; ++r)
              if ((jt * 64 + 16 * kt2 + 4 * g + r) > qg) St[mt][kt2][r] = -INFINITY;
        }
      }

      // ---- interleaved dual softmax ----
      float pm0 = -INFINITY, pm1 = -INFINITY;
#pragma unroll
      for (int kt2 = 0; kt2 < 4; ++kt2)
#pragma unroll
        for (int r = 0; r < 4; ++r) {
          pm0 = fmaxf(pm0, St[0][kt2][r]);
          pm1 = fmaxf(pm1, St[1][kt2][r]);
        }
      {
        float a0 = __shfl_xor(pm0, 16), a1 = __shfl_xor(pm1, 16);
        pm0 = fmaxf(pm0, a0); pm1 = fmaxf(pm1, a1);
        a0 = __shfl_xor(pm0, 32); a1 = __shfl_xor(pm1, 32);
        pm0 = fmaxf(pm0, a0); pm1 = fmaxf(pm1, a1);
      }
      float mo0 = m_run[0], mo1 = m_run[1];
      const bool need0 = !__all(pm0 <= mo0 + 8.0f);
      const bool need1 = !__all(pm1 <= mo1 + 8.0f);
      if (need0) {                          // defer-max: rescale only on growth
        float mn = fmaxf(mo0, pm0);
        float al = exp2f(mo0 - mn);
        l_run[0] *= al;
#pragma unroll
        for (int dt = 0; dt < 4; ++dt)
#pragma unroll
          for (int r = 0; r < 4; ++r) Ot[0][dt][r] *= al;
        m_run[0] = mn; mo0 = mn;
      }
      if (need1) {
        float mn = fmaxf(mo1, pm1);
        float al = exp2f(mo1 - mn);
        l_run[1] *= al;
#pragma unroll
        for (int dt = 0; dt < 4; ++dt)
#pragma unroll
          for (int r = 0; r < 4; ++r) Ot[1][dt][r] *= al;
        m_run[1] = mn; mo1 = mn;
      }
      f16x8 pB[2][2];   // [mt][kt] PV B-operand, assembled in-register
      float ts0 = 0.f, ts1 = 0.f;
#pragma unroll
      for (int kt2 = 0; kt2 < 4; ++kt2)
#pragma unroll
        for (int r = 0; r < 4; ++r) {
          float p0 = exp2f(St[0][kt2][r] - mo0);
          float p1 = exp2f(St[1][kt2][r] - mo1);
          ts0 += p0; ts1 += p1;
          pB[0][kt2 >> 1][(kt2 & 1) * 4 + r] = (f16)p0;
          pB[1][kt2 >> 1][(kt2 & 1) * 4 + r] = (f16)p1;
        }
      {
        float a0 = __shfl_xor(ts0, 16), a1 = __shfl_xor(ts1, 16);
        ts0 += a0; ts1 += a1;
        a0 = __shfl_xor(ts0, 32); a1 = __shfl_xor(ts1, 32);
        ts0 += a0; ts1 += a1;
      }
      l_run[0] += ts0;
      l_run[1] += ts1;

      // ---- O^T += V~^T . P~^T  (P direct from registers, V tau-permuted) ----
      __builtin_amdgcn_s_setprio(1);
#pragma unroll
      for (int kt = 0; kt < 2; ++kt)
#pragma unroll
        for (int dt = 0; dt < 4; ++dt) {
          int d = 16 * dt + lr;
          int s = (d + (d >> 3)) & 7;
          f16x8 vA = *reinterpret_cast<const f16x8*>(
              &Vt[cur][d * 64 + ((32 * kt + 8 * g) ^ (s << 3))]);
#pragma unroll
          for (int mt = 0; mt < 2; ++mt)
            Ot[mt][dt] = __builtin_amdgcn_mfma_f32_16x16x32_f16(
                vA, pB[mt][kt], Ot[mt][dt], 0, 0, 0);
        }
      __builtin_amdgcn_s_setprio(0);
    }

    // ---- epilogue: normalize, repack via Ks-aliased scratch, store ----
    __syncthreads();                      // all waves done reading Ks/Vt
    f16* scr = &Ks[0][0] + w * 2048;      // per-wave 32x64 region
#pragma unroll
    for (int mt = 0; mt < 2; ++mt) {
      float inv = 1.f / l_run[mt];
      int q = 16 * mt + lr;
#pragma unroll
      for (int dt = 0; dt < 4; ++dt) {
        f16x4 ok;
#pragma unroll
        for (int r = 0; r < 4; ++r) ok[r] = (f16)(Ot[mt][dt][r] * inv);
        *reinterpret_cast<f16x4*>(
            &scr[q * 64 + ((16 * dt + 4 * g) ^ ((q & 7) << 3))]) = ok;
      }
    }
    const int orow = l >> 1;
    const int ocol = (l & 1) * 32;
#pragma unroll
    for (int i = 0; i < 4; ++i) {
      f16x8 ov = *reinterpret_cast<const f16x8*>(
          &scr[orow * 64 + ((ocol + i * 8) ^ ((orow & 7) << 3))]);
      *reinterpret_cast<f16x8*>(
          &att[((size_t)(ob * NT + qbase + orow)) * NC + oh * HS + ocol + i * 8]) = ov;
    }
    __syncthreads();                      // protect scratch before next commit
  }
}

// ---------------------------------------------------------------------------
extern "C" void kernel_launch(void* const* d_in, const int* in_sizes, int n_in,
                              void* d_out, int out_size, void* d_ws, size_t ws_size,
                              hipStream_t stream)
{
  (void)in_sizes; (void)n_in; (void)out_size; (void)ws_size;
  const float* x     = (const float*)d_in[0];
  const float* Wqkv  = (const float*)d_in[1];
  const float* bqkv  = (const float*)d_in[2];
  const float* Wproj = (const float*)d_in[3];
  const float* bproj = (const float*)d_in[4];
  float* out = (float*)d_out;

  const size_t HE = (size_t)NB * NH * NT * HS;   // 8388608 elems per tensor
  f16* Qh  = (f16*)d_ws;
  f16* Kh  = Qh + HE;
  f16* Vh  = Kh + HE;
  f16* XA  = Vh + HE;            // Xh (pre-attn) aliases att (post-attn)
  f16* Wqt = XA + HE;            // 3072x1024
  f16* Wpt = Wqt + (size_t)3 * NC * NC;  // 1024x1024

  prep<<<dim3(4096 + 1024), 256, 0, stream>>>(x, Wqkv, Wproj, XA, Wqt, Wpt);
  gemm_f16<0><<<dim3(64 * 24), 256, 0, stream>>>(XA, Wqt, bqkv, Qh, Kh, Vh, nullptr, 24);
  flash_attn<<<dim3(1024), 128, 0, stream>>>(Qh, Kh, Vh, XA);
  gemm_f16<1><<<dim3(64 * 8), 256, 0, stream>>>(XA, Wpt, bproj, nullptr, nullptr, nullptr, out, 8);
}